// Round 8
// baseline (217.016 us; speedup 1.0000x reference)
//
#include <hip/hip_runtime.h>
#include <hip/hip_bf16.h>
#include <math.h>

#define B_  256
#define T_  512
#define D_  256
#define A_  50
#define EPS 1e-7f
#define NW  16   // waves per block

typedef short  short8  __attribute__((ext_vector_type(8)));
typedef float  floatx4 __attribute__((ext_vector_type(4)));

__device__ inline unsigned short f2bf(float f) {
    unsigned int u = __float_as_uint(f);
    u = (u + 0x7fffu + ((u >> 16) & 1u)) >> 16;   // RNE (inputs are finite)
    return (unsigned short)u;
}

// ---------------------------------------------------------------------------
// Prep: swizzle W [256][50] fp32 into bf16 B-fragment order for
// mfma_f32_16x16x32_bf16, zero-padded to N=64. Fragment (nt,ks), lane l,
// element j holds B[k][n] with n = nt*16 + (l&15), k = ks*32 + (l>>4)*8 + j.
// Layout: Wf[((nt*8+ks)*64 + l)*8 + j]. Also bias/u zero-padded to 64.
// (unchanged)
// ---------------------------------------------------------------------------
__global__ void prep_kernel(const float* __restrict__ W,
                            const float* __restrict__ bias,
                            const float* __restrict__ u,
                            unsigned short* __restrict__ Wf,
                            float* __restrict__ bu64)
{
    int idx = blockIdx.x * 256 + threadIdx.x;      // 0 .. 16383
    int j  = idx & 7;
    int l  = (idx >> 3) & 63;
    int ks = (idx >> 9) & 7;
    int nt = idx >> 12;
    int n  = nt * 16 + (l & 15);
    int k  = ks * 32 + (l >> 4) * 8 + j;
    float val = (n < A_) ? W[k * A_ + n] : 0.0f;
    Wf[idx] = f2bf(val);
    if (idx < 64) {
        bu64[idx]      = (idx < A_) ? bias[idx] : 0.0f;
        bu64[64 + idx] = (idx < A_) ? u[idx]    : 0.0f;
    }
}

// pack 4 floats -> 4 bf16 (hardware v_cvt_pk_bf16_f32, RNE)
__device__ inline void pack_bf4(short8& av, int base, float fx, float fy,
                                float fz, float fw)
{
    union { __hip_bfloat162 h2; int i; } c0, c1;
    c0.h2 = __float22bfloat162_rn(make_float2(fx, fy));
    c1.h2 = __float22bfloat162_rn(make_float2(fz, fw));
    av[base + 0] = (short)(c0.i & 0xffff);
    av[base + 1] = (short)((unsigned)c0.i >> 16);
    av[base + 2] = (short)(c1.i & 0xffff);
    av[base + 3] = (short)((unsigned)c1.i >> 16);
}

__device__ inline float4 shflxor4(float4 v, int m) {
    return make_float4(__shfl_xor(v.x, m), __shfl_xor(v.y, m),
                       __shfl_xor(v.z, m), __shfl_xor(v.w, m));
}
__device__ inline float4 add4(float4 a, float4 b) {
    return make_float4(a.x + b.x, a.y + b.y, a.z + b.z, a.w + b.w);
}
__device__ inline float4 sel4(bool p, float4 a, float4 b) {   // p ? a : b
    return make_float4(p ? a.x : b.x, p ? a.y : b.y,
                       p ? a.z : b.z, p ? a.w : b.w);
}
__device__ inline float4 mul4s(float4 a, float s) {
    return make_float4(a.x * s, a.y * s, a.z * s, a.w * s);
}

// ---------------------------------------------------------------------------
// R17: occupancy fix. R16 (streaming, ~50 live VGPR, no spill) landed at
// fused ~69 us vs the 21 us BW floor. Diagnosis: grid = 256 blocks on 256
// CUs = 1 block/CU = 16 waves/CU (50%), and each wave has long load-free
// serial windows (MFMA chain, tanhf, 15-step shfl butterfly, L2-latency
// pool loads) -> ~1/3 of achievable BW by Little's law.
//
// R17 splits each batch across 2 blocks: 512 blocks x 1024 threads,
// 2 blocks/CU (50 KB LDS, 64 VGPR) = 32 waves/CU. Each block does 256 rows
// (1 tile/wave — identical per-tile code/math as the R16 pass). Softmax
// denominator is deferred to a tiny combine kernel:
//   block 2b+h writes pp[2b+h][256] = unnormalized pooled partial and
//   ps[2b+h] = partial exp-sum;  out = (pp0+pp1) / (ps0+ps1+EPS).
// ---------------------------------------------------------------------------
__global__ __launch_bounds__(1024)
void fused_kernel(const float* __restrict__ x,
                  const unsigned short* __restrict__ Wf,
                  const float* __restrict__ bu64,
                  float* __restrict__ pp,
                  float* __restrict__ ps)
{
    __shared__ int4  Wl[2048];         // 32 KB: Wf staged, fragment order
    __shared__ float s_lds[256];       // 1 KB: exp-scores (this half)
    __shared__ float part[NW * 256];   // 16 KB: per-wave pooled partials

    const int tid  = threadIdx.x;
    const int w    = tid >> 6;      // 0..15
    const int l    = tid & 63;
    const int c    = l & 15;        // A-row owner within 16-row tile
    const int quad = l >> 4;        // k-slice / C-row-group
    const int bb   = blockIdx.x;    // 0..511
    const int bat  = bb >> 1;       // batch
    const int half = bb & 1;        // which 256-row half

    // Stage Wf -> LDS (32 KB, coalesced int4)
    {
        const int4* __restrict__ wsrc = (const int4*)Wf;
        Wl[tid]        = wsrc[tid];
        Wl[tid + 1024] = wsrc[tid + 1024];
    }

    const float*  __restrict__ xb  = x + (size_t)bat * T_ * D_;
    const short8* __restrict__ wl8 = (const short8*)Wl;

    float bnc[4], unc[4];
    #pragma unroll
    for (int nt = 0; nt < 4; nt++) {
        bnc[nt] = bu64[nt * 16 + c];
        unc[nt] = bu64[64 + nt * 16 + c];
    }
    __syncthreads();   // Wl ready

    // ---- ONE tile of 16 rows per wave: rows half*256 + [w*16, w*16+16) ----
    const int rowbase = w * 16;                       // local (s_lds/part) row
    const float4* __restrict__ xr =
        (const float4*)(xb + (size_t)(half * 256 + rowbase + c) * D_);

    floatx4 acc[4];
    #pragma unroll
    for (int nt = 0; nt < 4; nt++) acc[nt] = (floatx4){0.f, 0.f, 0.f, 0.f};

    // score phase: stream 2 granules per k-step (no pre[] array)
    #pragma unroll
    for (int ks = 0; ks < 8; ks++) {
        const float4 a0 = xr[8 * ks + 2 * quad];
        const float4 a1 = xr[8 * ks + 2 * quad + 1];
        short8 av;
        pack_bf4(av, 0, a0.x, a0.y, a0.z, a0.w);
        pack_bf4(av, 4, a1.x, a1.y, a1.z, a1.w);
        #pragma unroll
        for (int nt = 0; nt < 4; nt++) {
            const short8 bv = wl8[(nt * 8 + ks) * 64 + l];  // ds_read_b128
            acc[nt] = __builtin_amdgcn_mfma_f32_16x16x32_bf16(av, bv, acc[nt], 0, 0, 0);
        }
    }

    // scores for this wave's 16 rows (C layout: col=c, row=quad*4+r)
    #pragma unroll
    for (int r = 0; r < 4; r++) {
        float v = 0.0f;
        #pragma unroll
        for (int nt = 0; nt < 4; nt++)
            v += tanhf(acc[nt][r] + bnc[nt]) * unc[nt];
        #pragma unroll
        for (int off = 1; off < 16; off <<= 1)
            v += __shfl_xor(v, off, 16);
        if (c == 0)
            s_lds[rowbase + quad * 4 + r] = expf(v);
    }

    // weight = exp-score of THIS lane's row (same-wave LDS RAW, in-order)
    const float ec = s_lds[rowbase + c];

    // pool phase: re-load granules (L1/L2-hot) into the butterfly.
    // Level-1 pairs: xr[o] / xr[o+32], o = (j>>1)*8 + quad*2 + (j&1).
    float4 h8[8];
    #pragma unroll
    for (int j = 0; j < 8; j++) {
        const int o = (j >> 1) * 8 + quad * 2 + (j & 1);
        const float4 a = mul4s(xr[o],      ec);
        const float4 b = mul4s(xr[o + 32], ec);
        h8[j] = add4(sel4((c & 8) != 0, b, a),
                     shflxor4(sel4((c & 8) != 0, a, b), 8));
    }
    float4 h4[4];
    #pragma unroll
    for (int j = 0; j < 4; j++) {
        const float4 aa = h8[j], bb = h8[j + 4];
        h4[j] = add4(sel4((c & 4) != 0, bb, aa),
                     shflxor4(sel4((c & 4) != 0, aa, bb), 4));
    }
    float4 h2[2];
    #pragma unroll
    for (int j = 0; j < 2; j++) {
        const float4 aa = h4[j], bb = h4[j + 2];
        h2[j] = add4(sel4((c & 2) != 0, bb, aa),
                     shflxor4(sel4((c & 2) != 0, aa, bb), 2));
    }
    float4 accp;
    {
        const float4 aa = h2[0], bb = h2[1];
        accp = add4(sel4((c & 1) != 0, bb, aa),
                    shflxor4(sel4((c & 1) != 0, aa, bb), 1));
    }

    // lane (c,quad) owns granule g -> bijective float4 store, no masking
    const int g = (c >> 1) * 8 + quad * 2 + (c & 1);
    *(float4*)&part[w * 256 + g * 4] = accp;
    __syncthreads();   // all partials + all s_lds scores visible

    // ---- partial denominator: wave 0 sums this block's 256 exp-scores ----
    if (tid < 64) {
        float s = 0.0f;
        #pragma unroll
        for (int k = 0; k < 4; k++) s += s_lds[tid + k * 64];
        #pragma unroll
        for (int off = 1; off < 64; off <<= 1) s += __shfl_xor(s, off);
        if (tid == 0) ps[bb] = s;
    }

    // ---- partial pool: sum the 16 wave partials, store unnormalized ----
    if (tid < 256) {
        float o = 0.0f;
        #pragma unroll
        for (int wv = 0; wv < NW; wv++) o += part[wv * 256 + tid];
        pp[(size_t)bb * 256 + tid] = o;
    }
}

// ---------------------------------------------------------------------------
// Combine: out[b][d] = (pp[2b][d] + pp[2b+1][d]) / (ps[2b] + ps[2b+1] + EPS)
// ---------------------------------------------------------------------------
__global__ __launch_bounds__(256)
void combine_kernel(const float* __restrict__ pp,
                    const float* __restrict__ ps,
                    float* __restrict__ out)
{
    const int b = blockIdx.x;        // batch
    const int d = threadIdx.x;       // dim
    const float inv = 1.0f / (ps[2 * b] + ps[2 * b + 1] + EPS);
    const float v = pp[(size_t)(2 * b) * 256 + d] +
                    pp[(size_t)(2 * b + 1) * 256 + d];
    out[(size_t)b * 256 + d] = v * inv;
}

// ---------------------------------------------------------------------------
extern "C" void kernel_launch(void* const* d_in, const int* in_sizes, int n_in,
                              void* d_out, int out_size, void* d_ws, size_t ws_size,
                              hipStream_t stream)
{
    const float* x = (const float*)d_in[0];
    const float* W = (const float*)d_in[1];
    const float* b = (const float*)d_in[2];
    const float* u = (const float*)d_in[3];

    unsigned short* Wf   = (unsigned short*)d_ws;         // 16384 u16 (32 KB)
    float*          bu64 = (float*)(Wf + 16384);          // 128 f
    float*          pp   = bu64 + 128;                    // 512*256 f (512 KB)
    float*          ps   = pp + 512 * 256;                // 512 f
    float*          out  = (float*)d_out;

    prep_kernel    <<<64,  256,  0, stream>>>(W, b, u, Wf, bu64);
    fused_kernel   <<<512, 1024, 0, stream>>>(x, Wf, bu64, pp, ps);
    combine_kernel <<<256, 256,  0, stream>>>(pp, ps, out);
}